// Round 8
// baseline (190.485 us; speedup 1.0000x reference)
//
#include <hip/hip_runtime.h>

#define N_NODES 50000
#define N_EDGES 800000
#define IN_DIM  8
#define HD      128
#define NREP 16
#define NRANGE 16                               // node ranges per rep
#define RANGE_N (N_NODES / NRANGE)              // 3125 nodes per range
#define N_HISTB (NREP * NRANGE)                 // 256 hist jobs
#define N_HIST_BLOCKS (N_EDGES / 256)           // 3125 chunks of 256 edges
#define NTILES ((N_NODES + 63) / 64)            // 782 gemm tiles
#define N_SCAN_BLOCKS ((N_NODES + 255) / 256)   // 196
#define GRID_P1 (N_HISTB + NTILES + 1)          // 1039: hist | gemm | misc

typedef unsigned short ushort_t;
typedef unsigned int uint_t;
typedef __attribute__((ext_vector_type(8))) short short8;
typedef __attribute__((ext_vector_type(4))) float float4v;
typedef __attribute__((ext_vector_type(4))) int int4v;
typedef __attribute__((ext_vector_type(2))) uint_t uint2v;

static __device__ inline unsigned short f2bf(float f) {   // fp32 -> bf16 RNE
    unsigned u = __float_as_uint(f);
    unsigned r = (u + 0x7FFF + ((u >> 16) & 1)) >> 16;
    return (unsigned short)r;
}
static __device__ inline float bf2f(unsigned short b) {
    return __uint_as_float(((unsigned)b) << 16);
}

// ---------------------------------------------------------------------------
// Phase 1 (1039 blocks, one dispatch):
//   [0,256): LDS-histogram. Block = (rep, node-range), RANGE_N=3125.
//     Software-pipelined int4 edge loads; LDS atomics only; plain-store
//     cnt writeback. cnt needs no zeroing (hist writes every cell).
//   [256,1038): gemm tile. D = W2^T-frag x emb-frag (swapped operands):
//     col=node, row=hd -> packed 8B stores. W2 fragments staged through a
//     per-block 32KB LDS blob (64 coalesced loads + 8 ds_write_b128 per
//     thread, then 32 ds_read_b128) -- ~2.5x fewer mem instrs than the
//     256-scalar-load variant; this exact path was validated in r6.
//   block 1038: zero bsums; v3 = relu(W4) @ W3.
// ---------------------------------------------------------------------------
__global__ __launch_bounds__(256, 2)
void phase1_kernel(const float* __restrict__ emb,
                   const float* __restrict__ W2,
                   ushort_t* __restrict__ T16,
                   const int* __restrict__ ei,
                   int* __restrict__ cnt,
                   ushort_t* __restrict__ rank16,
                   const float* __restrict__ W4,
                   const float* __restrict__ W3,
                   float* __restrict__ v3,
                   int* __restrict__ bsums) {
    __shared__ __align__(16) char shmem[32768];  // hist: 12.5KB / gemm: 32KB
    int t = threadIdx.x;

    if (blockIdx.x < N_HISTB) {
        // ---- hist path ----
        uint_t* hcnt = (uint_t*)shmem;
        int rep   = blockIdx.x & (NREP - 1);
        int range = blockIdx.x / NREP;
        int rbase = range * RANGE_N;
        for (int i = t; i < RANGE_N; i += 256) hcnt[i] = 0u;
        __syncthreads();
        int g = t >> 6, lane = t & 63;
        int NC = (N_HIST_BLOCKS - rep + NREP - 1) / NREP;  // chunks of this rep
        int j = g;
        int4v rv = {0, 0, 0, 0};
        if (j < NC)
            rv = *(const int4v*)(ei + (rep + j * NREP) * 256 + lane * 4);
        while (j < NC) {
            int jn = j + 4;
            int4v nx = {0, 0, 0, 0};
            if (jn < NC)                 // prefetch next chunk's 4 edges
                nx = *(const int4v*)(ei + (rep + jn * NREP) * 256 + lane * 4);
            int e0 = (rep + j * NREP) * 256 + lane * 4;
#pragma unroll
            for (int q = 0; q < 4; ++q) {
                int lr = rv[q] - rbase;
                if ((unsigned)lr < (unsigned)RANGE_N) {
                    uint_t rk = atomicAdd(&hcnt[lr], 1u);
                    rank16[e0 + q] = (ushort_t)rk;
                }
            }
            rv = nx; j = jn;
        }
        __syncthreads();
        int* crow = cnt + rep * N_NODES + rbase;
        for (int i = t; i < RANGE_N; i += 256) crow[i] = (int)hcnt[i];
        return;
    }

    if (blockIdx.x == N_HISTB + NTILES) {
        // ---- misc: zero bsums; v3 = relu(W4) @ W3 ----
        bsums[t] = 0;
        if (t < HD) {
            float acc = 0.f;
            for (int k = 0; k < HD; ++k) {
                float w = W4[k];
                w = w > 0.f ? w : 0.f;
                acc += w * W3[k * HD + t];
            }
            v3[t] = acc;
        }
        return;
    }

    // ---- gemm path ----
    short8* sblob = (short8*)shmem;
    int tt   = blockIdx.x - N_HISTB;     // 0..781
    int wave = t >> 6;
    int lane = t & 63;
    int n16  = lane & 15;
    int quad = lane >> 4;

    // build blob: 2048 slots / 256 threads; slot layout
    // sblob[f=ct*4+ki][ln] elem j = bf16(W2[(ki*32+qq*8+j)*HD + ct*16+nn])
#pragma unroll
    for (int i = 0; i < 8; ++i) {
        int slot = t * 8 + i;
        int f    = slot >> 6;            // 0..31
        int ln   = slot & 63;
        int ct = f >> 2, ki = f & 3;
        int nn = ln & 15, qq = ln >> 4;
        short8 fr;
#pragma unroll
        for (int jj = 0; jj < 8; ++jj) {
            int k = ki * 32 + qq * 8 + jj;
            fr[jj] = (short)f2bf(W2[k * HD + ct * 16 + nn]);
        }
        sblob[slot] = fr;
    }

    int rowbase = tt * 64 + wave * 16;
    int row  = rowbase + n16;            // this lane's node (column of D)
    int rowc = row < N_NODES ? row : N_NODES - 1;
    const float4v* arow = (const float4v*)(emb + (size_t)rowc * HD);

    short8 efrag[4];                     // B-operand: emb row fragments
#pragma unroll
    for (int ki = 0; ki < 4; ++ki) {
        float4v lo = __builtin_nontemporal_load(&arow[ki * 8 + quad * 2]);
        float4v hi = __builtin_nontemporal_load(&arow[ki * 8 + quad * 2 + 1]);
        short8 a;
        a[0] = (short)f2bf(lo[0]); a[1] = (short)f2bf(lo[1]);
        a[2] = (short)f2bf(lo[2]); a[3] = (short)f2bf(lo[3]);
        a[4] = (short)f2bf(hi[0]); a[5] = (short)f2bf(hi[1]);
        a[6] = (short)f2bf(hi[2]); a[7] = (short)f2bf(hi[3]);
        efrag[ki] = a;
    }

    float4v acc[8];
#pragma unroll
    for (int ct = 0; ct < 8; ++ct) acc[ct] = (float4v){0.f, 0.f, 0.f, 0.f};

    __syncthreads();                     // blob ready
#pragma unroll
    for (int ki = 0; ki < 4; ++ki) {
        short8 wf[8];                    // 32 VGPRs live per ki
#pragma unroll
        for (int ct = 0; ct < 8; ++ct)
            wf[ct] = sblob[(ct * 4 + ki) * 64 + lane];
#pragma unroll
        for (int ct = 0; ct < 8; ++ct)
            acc[ct] = __builtin_amdgcn_mfma_f32_16x16x32_bf16(
                wf[ct], efrag[ki], acc[ct], 0, 0, 0);
    }

    // D layout (swapped): col = n16 -> node, row = quad*4+reg -> hd.
    if (row < N_NODES) {
        ushort_t* dstu = T16 + (size_t)row * HD + quad * 4;
#pragma unroll
        for (int ct = 0; ct < 8; ++ct) {
            uint2v v;
            v[0] = (uint_t)f2bf(acc[ct][0]) | ((uint_t)f2bf(acc[ct][1]) << 16);
            v[1] = (uint_t)f2bf(acc[ct][2]) | ((uint_t)f2bf(acc[ct][3]) << 16);
            *(uint2v*)(dstu + ct * 16) = v;
        }
    }
}

// ---------------------------------------------------------------------------
// Scan: per-node totals over reps; BLOCK-LOCAL exclusive off[] + bases[];
// cross-block exclusive fixup published directly into bsums[] via atomics.
// ---------------------------------------------------------------------------
__global__ void scan1_kernel(const int* __restrict__ cnt,
                             int* __restrict__ off,
                             int* __restrict__ bases,
                             int* __restrict__ bsums) {
    __shared__ int lds[256];
    int t = threadIdx.x;
    int n = blockIdx.x * 256 + t;
    int c[NREP];
    int tsum = 0;
#pragma unroll
    for (int r = 0; r < NREP; ++r) {
        c[r] = (n < N_NODES) ? cnt[r * N_NODES + n] : 0;
        tsum += c[r];
    }
    lds[t] = tsum;
    __syncthreads();
    for (int o = 1; o < 256; o <<= 1) {
        int add = (t >= o) ? lds[t - o] : 0;
        __syncthreads();
        lds[t] += add;
        __syncthreads();
    }
    int ex = lds[t] - tsum;              // exclusive prefix within block
    int total = lds[255];
    if (n < N_NODES) {
        off[n] = ex;
        int run = ex;
#pragma unroll
        for (int r = 0; r < NREP; ++r) {
            bases[r * N_NODES + n] = run;
            run += c[r];
        }
    }
    for (int bb = blockIdx.x + 1 + t; bb < N_SCAN_BLOCKS; bb += 256)
        atomicAdd(&bsums[bb], total);
}

// ---------------------------------------------------------------------------
// Pass 2: place packed (attr_bf16 << 16 | col) -- NO atomics.
// Stream-once inputs read nontemporally to preserve L2 for T16/bases.
// ---------------------------------------------------------------------------
__global__ void fill_kernel(const int* __restrict__ ei,
                            const float* __restrict__ attr,
                            const ushort_t* __restrict__ rank16,
                            const int* __restrict__ bases,
                            const int* __restrict__ bsums,
                            uint_t* __restrict__ packed) {
    int e = blockIdx.x * 256 + threadIdx.x;
    int rep = (e >> 8) & (NREP - 1);     // == chunk & (NREP-1), chunk = e>>8
    int r = __builtin_nontemporal_load(&ei[e]);
    int pos = bases[rep * N_NODES + r] + bsums[r >> 8]
            + (int)__builtin_nontemporal_load(&rank16[e]);
    uint_t p = ((uint_t)f2bf(__builtin_nontemporal_load(&attr[e])) << 16)
             | (uint_t)__builtin_nontemporal_load(&ei[N_EDGES + e]);
    packed[pos] = p;
}

// ---------------------------------------------------------------------------
// Owner-computes: out[n] = relu( x[n]@W1 + sum_c T16[c] + (sum attr)*v3 )
// 16 lanes/node; 8-deep outstanding 16B row-gathers per lane (latency-bound
// L2/L3 gather => ILP converts directly to time).
// ---------------------------------------------------------------------------
__global__ __launch_bounds__(256, 2)
void aggregate_kernel(const int* __restrict__ off,
                      const int* __restrict__ bsums,
                      const uint_t* __restrict__ packed,
                      const ushort_t* __restrict__ T16,
                      const float* __restrict__ x,
                      const float* __restrict__ W1,
                      const float* __restrict__ v3,
                      float* __restrict__ out) {
    int tid  = blockIdx.x * 256 + threadIdx.x;
    int node = tid >> 4;                 // 16 nodes per block
    int lane = tid & 15;                 // owns cols [8*lane, 8*lane+8)
    int s  = off[node] + bsums[node >> 8];
    int e1 = (node + 1 == N_NODES) ? N_EDGES
                                   : off[node + 1] + bsums[(node + 1) >> 8];
    int deg = e1 - s;

    float acc[8];
#pragma unroll
    for (int i = 0; i < 8; ++i) acc[i] = 0.f;
    float ssum = 0.f;

    for (int base = 0; base < deg; base += 16) {
        int rem = deg - base; if (rem > 16) rem = 16;
        uint_t p = 0;
        if (lane < rem) p = __builtin_nontemporal_load(&packed[s + base + lane]);
        ssum += __uint_as_float(p & 0xFFFF0000u);    // attr (bf16 hi), +0 if idle
        int col = (int)(p & 0xFFFFu);
        int j = 0;
        for (; j + 8 <= rem; j += 8) {   // 8 outstanding row-gathers
            int cc[8];
#pragma unroll
            for (int u = 0; u < 8; ++u) cc[u] = __shfl(col, j + u, 16);
            short8 tv[8];
#pragma unroll
            for (int u = 0; u < 8; ++u)
                tv[u] = ((const short8*)(T16 + (size_t)cc[u] * HD))[lane];
#pragma unroll
            for (int u = 0; u < 8; ++u)
#pragma unroll
                for (int i = 0; i < 8; ++i)
                    acc[i] += bf2f((ushort_t)tv[u][i]);
        }
        for (; j < rem; ++j) {
            int c = __shfl(col, j, 16);
            short8 tv = ((const short8*)(T16 + (size_t)c * HD))[lane];
#pragma unroll
            for (int i = 0; i < 8; ++i)
                acc[i] += bf2f((ushort_t)tv[i]);
        }
    }
    // reduce ssum across the 16-lane group
    for (int o = 8; o; o >>= 1) ssum += __shfl_xor(ssum, o, 16);

    const float4v* v3p = (const float4v*)v3;
    float4v b0 = v3p[lane * 2], b1 = v3p[lane * 2 + 1];
    acc[0] += ssum * b0[0]; acc[1] += ssum * b0[1];
    acc[2] += ssum * b0[2]; acc[3] += ssum * b0[3];
    acc[4] += ssum * b1[0]; acc[5] += ssum * b1[1];
    acc[6] += ssum * b1[2]; acc[7] += ssum * b1[3];
#pragma unroll
    for (int i = 0; i < IN_DIM; ++i) {
        float xi = x[node * IN_DIM + i];
        const float4v* wp = (const float4v*)(W1 + i * HD);
        float4v w0 = wp[lane * 2], w1 = wp[lane * 2 + 1];
        acc[0] += xi * w0[0]; acc[1] += xi * w0[1];
        acc[2] += xi * w0[2]; acc[3] += xi * w0[3];
        acc[4] += xi * w1[0]; acc[5] += xi * w1[1];
        acc[6] += xi * w1[2]; acc[7] += xi * w1[3];
    }
    float4v o0, o1;
    o0[0] = fmaxf(acc[0], 0.f); o0[1] = fmaxf(acc[1], 0.f);
    o0[2] = fmaxf(acc[2], 0.f); o0[3] = fmaxf(acc[3], 0.f);
    o1[0] = fmaxf(acc[4], 0.f); o1[1] = fmaxf(acc[5], 0.f);
    o1[2] = fmaxf(acc[6], 0.f); o1[3] = fmaxf(acc[7], 0.f);
    float4v* op = (float4v*)(out + (size_t)node * HD);
    __builtin_nontemporal_store(o0, op + lane * 2);
    __builtin_nontemporal_store(o1, op + lane * 2 + 1);
}

extern "C" void kernel_launch(void* const* d_in, const int* in_sizes, int n_in,
                              void* d_out, int out_size, void* d_ws, size_t ws_size,
                              hipStream_t stream) {
    const float* x    = (const float*)d_in[0];   // [N,8]
    const int*   ei   = (const int*)  d_in[1];   // [2,E]
    const float* attr = (const float*)d_in[2];   // [E,1]
    const float* emb  = (const float*)d_in[3];   // [N,128]
    const float* W1   = (const float*)d_in[4];   // [8,128]
    const float* W2   = (const float*)d_in[5];   // [128,128]
    const float* W3   = (const float*)d_in[6];   // [128,128]
    const float* W4   = (const float*)d_in[7];   // [1,128]
    float* out = (float*)d_out;                  // [N,128]

    // workspace layout (~24.2 MB)
    char* w = (char*)d_ws;
    uint_t*   packed = (uint_t*)w;                                   // 3.2 MB
    ushort_t* T16    = (ushort_t*)(w + (size_t)N_EDGES * 4);         // 12.8 MB
    int*      off    = (int*)((char*)T16 + (size_t)N_NODES * HD * 2);// N+4
    int*      bases  = off + N_NODES + 4;        // NREP * N_NODES   // 3.2 MB
    int*      cnt    = bases + NREP * N_NODES;   // NREP * N_NODES   // 3.2 MB
    int*      bsums  = cnt + NREP * N_NODES;     // 256
    float*    v3     = (float*)(bsums + 256);    // 128
    ushort_t* rank16 = (ushort_t*)(v3 + HD);     // 1.6 MB

    phase1_kernel<<<GRID_P1, 256, 0, stream>>>(
        emb, W2, T16, ei, cnt, rank16, W4, W3, v3, bsums);
    scan1_kernel <<<N_SCAN_BLOCKS, 256, 0, stream>>>(cnt, off, bases, bsums);
    fill_kernel  <<<N_HIST_BLOCKS, 256, 0, stream>>>(ei, attr, rank16, bases, bsums, packed);
    aggregate_kernel<<<(N_NODES * 16) / 256, 256, 0, stream>>>(
        off, bsums, packed, T16, x, W1, v3, out);
}

// Round 9
// 187.405 us; speedup vs baseline: 1.0164x; 1.0164x over previous
//
#include <hip/hip_runtime.h>

#define N_NODES 50000
#define N_EDGES 800000
#define IN_DIM  8
#define HD      128
#define NREP 16
#define NRANGE 4                                // node ranges per rep
#define RANGE_N (N_NODES / NRANGE)              // 12500 nodes per range
#define N_HISTB (NREP * NRANGE)                 // 64 hist jobs
#define N_HIST_BLOCKS (N_EDGES / 256)           // 3125 chunks of 256 edges
#define NTILES ((N_NODES + 63) / 64)            // 782 gemm tiles
#define N_SCAN_BLOCKS ((N_NODES + 255) / 256)   // 196
#define GRID_P1 (N_HISTB + NTILES + 1)          // 847: hist | gemm | misc

typedef unsigned short ushort_t;
typedef unsigned int uint_t;
typedef __attribute__((ext_vector_type(8))) short short8;
typedef __attribute__((ext_vector_type(4))) float float4v;
typedef __attribute__((ext_vector_type(4))) int int4v;
typedef __attribute__((ext_vector_type(2))) uint_t uint2v;

static __device__ inline unsigned short f2bf(float f) {   // fp32 -> bf16 RNE
    unsigned u = __float_as_uint(f);
    unsigned r = (u + 0x7FFF + ((u >> 16) & 1)) >> 16;
    return (unsigned short)r;
}
static __device__ inline float bf2f(unsigned short b) {
    return __uint_as_float(((unsigned)b) << 16);
}

// ---------------------------------------------------------------------------
// Phase 1 (847 blocks, one dispatch):
//   [0,64): LDS-histogram. Block = (rep, node-range), RANGE_N=12500 (50KB).
//     NRANGE=4 cuts the redundant rep-scan 4x vs NRANGE=16 (each block still
//     reads its rep's full edge list; fewer blocks re-reading it). Software-
//     pipelined int4 loads; LDS atomics only; plain-store cnt writeback.
//     cnt needs no zeroing (hist writes every cell).
//   [64,846): gemm tile. D = W2^T-frag x emb-frag (swapped operands):
//     col=node, row=hd -> packed 8B stores. W2 fragments built per-ki
//     DIRECTLY from L1/L2-hot W2 (r7-proven; the r8 LDS-blob variant was a
//     32-way bank-conflict regression -- do not reintroduce).
//   block 846: zero bsums; v3 = relu(W4) @ W3.
// ---------------------------------------------------------------------------
__global__ __launch_bounds__(256, 2)
void phase1_kernel(const float* __restrict__ emb,
                   const float* __restrict__ W2,
                   ushort_t* __restrict__ T16,
                   const int* __restrict__ ei,
                   int* __restrict__ cnt,
                   ushort_t* __restrict__ rank16,
                   const float* __restrict__ W4,
                   const float* __restrict__ W3,
                   float* __restrict__ v3,
                   int* __restrict__ bsums) {
    __shared__ uint_t hcnt[RANGE_N];     // 50 KB (hist blocks only)
    int t = threadIdx.x;

    if (blockIdx.x < N_HISTB) {
        // ---- hist path ----
        int rep   = blockIdx.x & (NREP - 1);
        int range = blockIdx.x / NREP;
        int rbase = range * RANGE_N;
        for (int i = t; i < RANGE_N; i += 256) hcnt[i] = 0u;
        __syncthreads();
        int g = t >> 6, lane = t & 63;
        int NC = (N_HIST_BLOCKS - rep + NREP - 1) / NREP;  // chunks of this rep
        int j = g;
        int4v rv = {0, 0, 0, 0};
        if (j < NC)
            rv = *(const int4v*)(ei + (rep + j * NREP) * 256 + lane * 4);
        while (j < NC) {
            int jn = j + 4;
            int4v nx = {0, 0, 0, 0};
            if (jn < NC)                 // prefetch next chunk's 4 edges
                nx = *(const int4v*)(ei + (rep + jn * NREP) * 256 + lane * 4);
            int e0 = (rep + j * NREP) * 256 + lane * 4;
#pragma unroll
            for (int q = 0; q < 4; ++q) {
                int lr = rv[q] - rbase;
                if ((unsigned)lr < (unsigned)RANGE_N) {
                    uint_t rk = atomicAdd(&hcnt[lr], 1u);
                    rank16[e0 + q] = (ushort_t)rk;
                }
            }
            rv = nx; j = jn;
        }
        __syncthreads();
        int* crow = cnt + rep * N_NODES + rbase;
        for (int i = t; i < RANGE_N; i += 256) crow[i] = (int)hcnt[i];
        return;
    }

    if (blockIdx.x == N_HISTB + NTILES) {
        // ---- misc: zero bsums; v3 = relu(W4) @ W3 ----
        bsums[t] = 0;
        if (t < HD) {
            float acc = 0.f;
            for (int k = 0; k < HD; ++k) {
                float w = W4[k];
                w = w > 0.f ? w : 0.f;
                acc += w * W3[k * HD + t];
            }
            v3[t] = acc;
        }
        return;
    }

    // ---- gemm path ----
    int tt   = blockIdx.x - N_HISTB;     // 0..781
    int wave = t >> 6;
    int lane = t & 63;
    int n16  = lane & 15;
    int quad = lane >> 4;

    int rowbase = tt * 64 + wave * 16;
    int row  = rowbase + n16;            // this lane's node (column of D)
    int rowc = row < N_NODES ? row : N_NODES - 1;
    const float4v* arow = (const float4v*)(emb + (size_t)rowc * HD);

    short8 efrag[4];                     // B-operand: emb row fragments
#pragma unroll
    for (int ki = 0; ki < 4; ++ki) {
        float4v lo = __builtin_nontemporal_load(&arow[ki * 8 + quad * 2]);
        float4v hi = __builtin_nontemporal_load(&arow[ki * 8 + quad * 2 + 1]);
        short8 a;
        a[0] = (short)f2bf(lo[0]); a[1] = (short)f2bf(lo[1]);
        a[2] = (short)f2bf(lo[2]); a[3] = (short)f2bf(lo[3]);
        a[4] = (short)f2bf(hi[0]); a[5] = (short)f2bf(hi[1]);
        a[6] = (short)f2bf(hi[2]); a[7] = (short)f2bf(hi[3]);
        efrag[ki] = a;
    }

    float4v acc[8];
#pragma unroll
    for (int ct = 0; ct < 8; ++ct) acc[ct] = (float4v){0.f, 0.f, 0.f, 0.f};

    // A-operand built per-ki from W2 (64 KB, L1/L2-hot across 782 blocks):
    // wf[ct][j] = bf16(W2[(ki*32 + quad*8 + j)*HD + ct*16 + n16])
    const float* wbase = W2 + (quad * 8) * HD + n16;
#pragma unroll
    for (int ki = 0; ki < 4; ++ki) {
        const float* wk = wbase + ki * 32 * HD;
        short8 wf[8];                    // 32 VGPRs live per ki
#pragma unroll
        for (int ct = 0; ct < 8; ++ct)
#pragma unroll
            for (int j = 0; j < 8; ++j)
                wf[ct][j] = (short)f2bf(wk[j * HD + ct * 16]);
#pragma unroll
        for (int ct = 0; ct < 8; ++ct)
            acc[ct] = __builtin_amdgcn_mfma_f32_16x16x32_bf16(
                wf[ct], efrag[ki], acc[ct], 0, 0, 0);
    }

    // D layout (swapped): col = n16 -> node, row = quad*4+reg -> hd.
    if (row < N_NODES) {
        ushort_t* dstu = T16 + (size_t)row * HD + quad * 4;
#pragma unroll
        for (int ct = 0; ct < 8; ++ct) {
            uint2v v;
            v[0] = (uint_t)f2bf(acc[ct][0]) | ((uint_t)f2bf(acc[ct][1]) << 16);
            v[1] = (uint_t)f2bf(acc[ct][2]) | ((uint_t)f2bf(acc[ct][3]) << 16);
            *(uint2v*)(dstu + ct * 16) = v;
        }
    }
}

// ---------------------------------------------------------------------------
// Scan: per-node totals over reps; BLOCK-LOCAL exclusive off[] + bases[];
// cross-block exclusive fixup published directly into bsums[] via atomics.
// ---------------------------------------------------------------------------
__global__ void scan1_kernel(const int* __restrict__ cnt,
                             int* __restrict__ off,
                             int* __restrict__ bases,
                             int* __restrict__ bsums) {
    __shared__ int lds[256];
    int t = threadIdx.x;
    int n = blockIdx.x * 256 + t;
    int c[NREP];
    int tsum = 0;
#pragma unroll
    for (int r = 0; r < NREP; ++r) {
        c[r] = (n < N_NODES) ? cnt[r * N_NODES + n] : 0;
        tsum += c[r];
    }
    lds[t] = tsum;
    __syncthreads();
    for (int o = 1; o < 256; o <<= 1) {
        int add = (t >= o) ? lds[t - o] : 0;
        __syncthreads();
        lds[t] += add;
        __syncthreads();
    }
    int ex = lds[t] - tsum;              // exclusive prefix within block
    int total = lds[255];
    if (n < N_NODES) {
        off[n] = ex;
        int run = ex;
#pragma unroll
        for (int r = 0; r < NREP; ++r) {
            bases[r * N_NODES + n] = run;
            run += c[r];
        }
    }
    for (int bb = blockIdx.x + 1 + t; bb < N_SCAN_BLOCKS; bb += 256)
        atomicAdd(&bsums[bb], total);
}

// ---------------------------------------------------------------------------
// Pass 2: place packed (attr_bf16 << 16 | col) -- NO atomics.
// ---------------------------------------------------------------------------
__global__ void fill_kernel(const int* __restrict__ ei,
                            const float* __restrict__ attr,
                            const ushort_t* __restrict__ rank16,
                            const int* __restrict__ bases,
                            const int* __restrict__ bsums,
                            uint_t* __restrict__ packed) {
    int e = blockIdx.x * 256 + threadIdx.x;
    int rep = (e >> 8) & (NREP - 1);     // == chunk & (NREP-1), chunk = e>>8
    int r = ei[e];
    int pos = bases[rep * N_NODES + r] + bsums[r >> 8] + (int)rank16[e];
    uint_t p = ((uint_t)f2bf(attr[e]) << 16) | (uint_t)ei[N_EDGES + e];
    packed[pos] = p;
}

// ---------------------------------------------------------------------------
// Owner-computes: out[n] = relu( x[n]@W1 + sum_c T16[c] + (sum attr)*v3 )
// 16 lanes/node, ushort8 (16 B) per lane per neighbor row; MLP-4 gathers.
// ---------------------------------------------------------------------------
__global__ void aggregate_kernel(const int* __restrict__ off,
                                 const int* __restrict__ bsums,
                                 const uint_t* __restrict__ packed,
                                 const ushort_t* __restrict__ T16,
                                 const float* __restrict__ x,
                                 const float* __restrict__ W1,
                                 const float* __restrict__ v3,
                                 float* __restrict__ out) {
    int tid  = blockIdx.x * 256 + threadIdx.x;
    int node = tid >> 4;                 // 16 nodes per block
    int lane = tid & 15;                 // owns cols [8*lane, 8*lane+8)
    int s  = off[node] + bsums[node >> 8];
    int e1 = (node + 1 == N_NODES) ? N_EDGES
                                   : off[node + 1] + bsums[(node + 1) >> 8];
    int deg = e1 - s;

    float acc[8];
#pragma unroll
    for (int i = 0; i < 8; ++i) acc[i] = 0.f;
    float ssum = 0.f;

    for (int base = 0; base < deg; base += 16) {
        int rem = deg - base; if (rem > 16) rem = 16;
        uint_t p = 0;
        if (lane < rem) p = __builtin_nontemporal_load(&packed[s + base + lane]);
        ssum += __uint_as_float(p & 0xFFFF0000u);    // attr (bf16 hi), +0 if idle
        int col = (int)(p & 0xFFFFu);
        int j = 0;
        for (; j + 4 <= rem; j += 4) {
            int c0 = __shfl(col, j + 0, 16);
            int c1 = __shfl(col, j + 1, 16);
            int c2 = __shfl(col, j + 2, 16);
            int c3 = __shfl(col, j + 3, 16);
            short8 t0 = ((const short8*)(T16 + (size_t)c0 * HD))[lane];
            short8 t1 = ((const short8*)(T16 + (size_t)c1 * HD))[lane];
            short8 t2 = ((const short8*)(T16 + (size_t)c2 * HD))[lane];
            short8 t3 = ((const short8*)(T16 + (size_t)c3 * HD))[lane];
#pragma unroll
            for (int i = 0; i < 8; ++i)
                acc[i] += (bf2f((ushort_t)t0[i]) + bf2f((ushort_t)t1[i]))
                        + (bf2f((ushort_t)t2[i]) + bf2f((ushort_t)t3[i]));
        }
        for (; j < rem; ++j) {
            int c = __shfl(col, j, 16);
            short8 tv = ((const short8*)(T16 + (size_t)c * HD))[lane];
#pragma unroll
            for (int i = 0; i < 8; ++i)
                acc[i] += bf2f((ushort_t)tv[i]);
        }
    }
    // reduce ssum across the 16-lane group
    for (int o = 8; o; o >>= 1) ssum += __shfl_xor(ssum, o, 16);

    const float4v* v3p = (const float4v*)v3;
    float4v b0 = v3p[lane * 2], b1 = v3p[lane * 2 + 1];
    acc[0] += ssum * b0[0]; acc[1] += ssum * b0[1];
    acc[2] += ssum * b0[2]; acc[3] += ssum * b0[3];
    acc[4] += ssum * b1[0]; acc[5] += ssum * b1[1];
    acc[6] += ssum * b1[2]; acc[7] += ssum * b1[3];
#pragma unroll
    for (int i = 0; i < IN_DIM; ++i) {
        float xi = x[node * IN_DIM + i];
        const float4v* wp = (const float4v*)(W1 + i * HD);
        float4v w0 = wp[lane * 2], w1 = wp[lane * 2 + 1];
        acc[0] += xi * w0[0]; acc[1] += xi * w0[1];
        acc[2] += xi * w0[2]; acc[3] += xi * w0[3];
        acc[4] += xi * w1[0]; acc[5] += xi * w1[1];
        acc[6] += xi * w1[2]; acc[7] += xi * w1[3];
    }
    float4v o0, o1;
    o0[0] = fmaxf(acc[0], 0.f); o0[1] = fmaxf(acc[1], 0.f);
    o0[2] = fmaxf(acc[2], 0.f); o0[3] = fmaxf(acc[3], 0.f);
    o1[0] = fmaxf(acc[4], 0.f); o1[1] = fmaxf(acc[5], 0.f);
    o1[2] = fmaxf(acc[6], 0.f); o1[3] = fmaxf(acc[7], 0.f);
    float4v* op = (float4v*)(out + (size_t)node * HD);
    __builtin_nontemporal_store(o0, op + lane * 2);
    __builtin_nontemporal_store(o1, op + lane * 2 + 1);
}

extern "C" void kernel_launch(void* const* d_in, const int* in_sizes, int n_in,
                              void* d_out, int out_size, void* d_ws, size_t ws_size,
                              hipStream_t stream) {
    const float* x    = (const float*)d_in[0];   // [N,8]
    const int*   ei   = (const int*)  d_in[1];   // [2,E]
    const float* attr = (const float*)d_in[2];   // [E,1]
    const float* emb  = (const float*)d_in[3];   // [N,128]
    const float* W1   = (const float*)d_in[4];   // [8,128]
    const float* W2   = (const float*)d_in[5];   // [128,128]
    const float* W3   = (const float*)d_in[6];   // [128,128]
    const float* W4   = (const float*)d_in[7];   // [1,128]
    float* out = (float*)d_out;                  // [N,128]

    // workspace layout (~24.2 MB)
    char* w = (char*)d_ws;
    uint_t*   packed = (uint_t*)w;                                   // 3.2 MB
    ushort_t* T16    = (ushort_t*)(w + (size_t)N_EDGES * 4);         // 12.8 MB
    int*      off    = (int*)((char*)T16 + (size_t)N_NODES * HD * 2);// N+4
    int*      bases  = off + N_NODES + 4;        // NREP * N_NODES   // 3.2 MB
    int*      cnt    = bases + NREP * N_NODES;   // NREP * N_NODES   // 3.2 MB
    int*      bsums  = cnt + NREP * N_NODES;     // 256
    float*    v3     = (float*)(bsums + 256);    // 128
    ushort_t* rank16 = (ushort_t*)(v3 + HD);     // 1.6 MB

    phase1_kernel<<<GRID_P1, 256, 0, stream>>>(
        emb, W2, T16, ei, cnt, rank16, W4, W3, v3, bsums);
    scan1_kernel <<<N_SCAN_BLOCKS, 256, 0, stream>>>(cnt, off, bases, bsums);
    fill_kernel  <<<N_HIST_BLOCKS, 256, 0, stream>>>(ei, attr, rank16, bases, bsums, packed);
    aggregate_kernel<<<(N_NODES * 16) / 256, 256, 0, stream>>>(
        off, bsums, packed, T16, x, W1, v3, out);
}

// Round 10
// 173.200 us; speedup vs baseline: 1.0998x; 1.0820x over previous
//
#include <hip/hip_runtime.h>

#define N_NODES 50000
#define N_EDGES 800000
#define IN_DIM  8
#define HD      128
#define NREP 16
#define NRANGE 16                               // node ranges per rep
#define RANGE_N (N_NODES / NRANGE)              // 3125 nodes per range
#define N_HISTB (NREP * NRANGE)                 // 256 hist jobs
#define N_HIST_BLOCKS (N_EDGES / 256)           // 3125 chunks of 256 edges
#define NTILES ((N_NODES + 63) / 64)            // 782 gemm tiles
#define N_SCAN_BLOCKS ((N_NODES + 255) / 256)   // 196
#define GRID_P1 (N_HISTB + NTILES + 1)          // 1039: hist | gemm | misc

typedef unsigned short ushort_t;
typedef unsigned int uint_t;
typedef __attribute__((ext_vector_type(8))) short short8;
typedef __attribute__((ext_vector_type(4))) float float4v;
typedef __attribute__((ext_vector_type(4))) int int4v;
typedef __attribute__((ext_vector_type(2))) uint_t uint2v;

static __device__ inline unsigned short f2bf(float f) {   // fp32 -> bf16 RNE
    unsigned u = __float_as_uint(f);
    unsigned r = (u + 0x7FFF + ((u >> 16) & 1)) >> 16;
    return (unsigned short)r;
}
static __device__ inline float bf2f(unsigned short b) {
    return __uint_as_float(((unsigned)b) << 16);
}

// ---------------------------------------------------------------------------
// Phase 1 (1039 blocks, one dispatch) -- r7-proven config + DEPTH-4 hist
// prefetch (the one change this round):
//   [0,256): LDS-histogram. Block = (rep, node-range), RANGE_N=3125 (12.5KB).
//     Each wave keeps FOUR int4 edge-loads in flight (buf[4], fetch j+16
//     while processing j) -- r9 showed depth-1 prefetch leaves the loop
//     latency-bound at ~900cy/iter (phase1 pinned at 45us across configs).
//     LDS atomics only; plain-store cnt writeback; cnt needs no zeroing.
//   [256,1038): gemm tile. D = W2^T-frag x emb-frag (swapped operands):
//     col=node, row=hd -> packed 8B stores. W2 fragments built per-ki
//     DIRECTLY from L1/L2-hot W2 (r7-proven; r8's LDS-blob was a 32-way
//     bank-conflict regression).
//   block 1038: zero bsums; v3 = relu(W4) @ W3.
// ---------------------------------------------------------------------------
__global__ __launch_bounds__(256, 2)
void phase1_kernel(const float* __restrict__ emb,
                   const float* __restrict__ W2,
                   ushort_t* __restrict__ T16,
                   const int* __restrict__ ei,
                   int* __restrict__ cnt,
                   ushort_t* __restrict__ rank16,
                   const float* __restrict__ W4,
                   const float* __restrict__ W3,
                   float* __restrict__ v3,
                   int* __restrict__ bsums) {
    __shared__ uint_t hcnt[RANGE_N];     // 12.5 KB
    int t = threadIdx.x;

    if (blockIdx.x < N_HISTB) {
        // ---- hist path: depth-4 software pipeline ----
        int rep   = blockIdx.x & (NREP - 1);
        int range = blockIdx.x / NREP;
        int rbase = range * RANGE_N;
        for (int i = t; i < RANGE_N; i += 256) hcnt[i] = 0u;
        __syncthreads();
        int g = t >> 6, lane = t & 63;
        int NC = (N_HIST_BLOCKS - rep + NREP - 1) / NREP;  // chunks of this rep
        int4v buf[4];
#pragma unroll
        for (int p = 0; p < 4; ++p) {    // fill pipeline: my chunks g+4p
            int jj = g + 4 * p;
            if (jj < NC)
                buf[p] = *(const int4v*)(ei + (rep + jj * NREP) * 256 + lane * 4);
        }
        int j = g;
        while (j < NC) {
            int4v rv = buf[0];
            buf[0] = buf[1]; buf[1] = buf[2]; buf[2] = buf[3];
            int jf = j + 16;             // fetch 4-ahead of my stream
            if (jf < NC)
                buf[3] = *(const int4v*)(ei + (rep + jf * NREP) * 256 + lane * 4);
            int e0 = (rep + j * NREP) * 256 + lane * 4;
#pragma unroll
            for (int q = 0; q < 4; ++q) {
                int lr = rv[q] - rbase;
                if ((unsigned)lr < (unsigned)RANGE_N) {
                    uint_t rk = atomicAdd(&hcnt[lr], 1u);
                    rank16[e0 + q] = (ushort_t)rk;
                }
            }
            j += 4;
        }
        __syncthreads();
        int* crow = cnt + rep * N_NODES + rbase;
        for (int i = t; i < RANGE_N; i += 256) crow[i] = (int)hcnt[i];
        return;
    }

    if (blockIdx.x == N_HISTB + NTILES) {
        // ---- misc: zero bsums; v3 = relu(W4) @ W3 ----
        bsums[t] = 0;
        if (t < HD) {
            float acc = 0.f;
            for (int k = 0; k < HD; ++k) {
                float w = W4[k];
                w = w > 0.f ? w : 0.f;
                acc += w * W3[k * HD + t];
            }
            v3[t] = acc;
        }
        return;
    }

    // ---- gemm path ----
    int tt   = blockIdx.x - N_HISTB;     // 0..781
    int wave = t >> 6;
    int lane = t & 63;
    int n16  = lane & 15;
    int quad = lane >> 4;

    int rowbase = tt * 64 + wave * 16;
    int row  = rowbase + n16;            // this lane's node (column of D)
    int rowc = row < N_NODES ? row : N_NODES - 1;
    const float4v* arow = (const float4v*)(emb + (size_t)rowc * HD);

    short8 efrag[4];                     // B-operand: emb row fragments
#pragma unroll
    for (int ki = 0; ki < 4; ++ki) {
        float4v lo = __builtin_nontemporal_load(&arow[ki * 8 + quad * 2]);
        float4v hi = __builtin_nontemporal_load(&arow[ki * 8 + quad * 2 + 1]);
        short8 a;
        a[0] = (short)f2bf(lo[0]); a[1] = (short)f2bf(lo[1]);
        a[2] = (short)f2bf(lo[2]); a[3] = (short)f2bf(lo[3]);
        a[4] = (short)f2bf(hi[0]); a[5] = (short)f2bf(hi[1]);
        a[6] = (short)f2bf(hi[2]); a[7] = (short)f2bf(hi[3]);
        efrag[ki] = a;
    }

    float4v acc[8];
#pragma unroll
    for (int ct = 0; ct < 8; ++ct) acc[ct] = (float4v){0.f, 0.f, 0.f, 0.f};

    // A-operand built per-ki from W2 (64 KB, L1/L2-hot across 782 blocks):
    // wf[ct][j] = bf16(W2[(ki*32 + quad*8 + j)*HD + ct*16 + n16])
    const float* wbase = W2 + (quad * 8) * HD + n16;
#pragma unroll
    for (int ki = 0; ki < 4; ++ki) {
        const float* wk = wbase + ki * 32 * HD;
        short8 wf[8];                    // 32 VGPRs live per ki
#pragma unroll
        for (int ct = 0; ct < 8; ++ct)
#pragma unroll
            for (int j = 0; j < 8; ++j)
                wf[ct][j] = (short)f2bf(wk[j * HD + ct * 16]);
#pragma unroll
        for (int ct = 0; ct < 8; ++ct)
            acc[ct] = __builtin_amdgcn_mfma_f32_16x16x32_bf16(
                wf[ct], efrag[ki], acc[ct], 0, 0, 0);
    }

    // D layout (swapped): col = n16 -> node, row = quad*4+reg -> hd.
    if (row < N_NODES) {
        ushort_t* dstu = T16 + (size_t)row * HD + quad * 4;
#pragma unroll
        for (int ct = 0; ct < 8; ++ct) {
            uint2v v;
            v[0] = (uint_t)f2bf(acc[ct][0]) | ((uint_t)f2bf(acc[ct][1]) << 16);
            v[1] = (uint_t)f2bf(acc[ct][2]) | ((uint_t)f2bf(acc[ct][3]) << 16);
            *(uint2v*)(dstu + ct * 16) = v;
        }
    }
}

// ---------------------------------------------------------------------------
// Scan: per-node totals over reps; BLOCK-LOCAL exclusive off[] + bases[];
// cross-block exclusive fixup published directly into bsums[] via atomics.
// ---------------------------------------------------------------------------
__global__ void scan1_kernel(const int* __restrict__ cnt,
                             int* __restrict__ off,
                             int* __restrict__ bases,
                             int* __restrict__ bsums) {
    __shared__ int lds[256];
    int t = threadIdx.x;
    int n = blockIdx.x * 256 + t;
    int c[NREP];
    int tsum = 0;
#pragma unroll
    for (int r = 0; r < NREP; ++r) {
        c[r] = (n < N_NODES) ? cnt[r * N_NODES + n] : 0;
        tsum += c[r];
    }
    lds[t] = tsum;
    __syncthreads();
    for (int o = 1; o < 256; o <<= 1) {
        int add = (t >= o) ? lds[t - o] : 0;
        __syncthreads();
        lds[t] += add;
        __syncthreads();
    }
    int ex = lds[t] - tsum;              // exclusive prefix within block
    int total = lds[255];
    if (n < N_NODES) {
        off[n] = ex;
        int run = ex;
#pragma unroll
        for (int r = 0; r < NREP; ++r) {
            bases[r * N_NODES + n] = run;
            run += c[r];
        }
    }
    for (int bb = blockIdx.x + 1 + t; bb < N_SCAN_BLOCKS; bb += 256)
        atomicAdd(&bsums[bb], total);
}

// ---------------------------------------------------------------------------
// Pass 2: place packed (attr_bf16 << 16 | col) -- NO atomics.
// ---------------------------------------------------------------------------
__global__ void fill_kernel(const int* __restrict__ ei,
                            const float* __restrict__ attr,
                            const ushort_t* __restrict__ rank16,
                            const int* __restrict__ bases,
                            const int* __restrict__ bsums,
                            uint_t* __restrict__ packed) {
    int e = blockIdx.x * 256 + threadIdx.x;
    int rep = (e >> 8) & (NREP - 1);     // == chunk & (NREP-1), chunk = e>>8
    int r = ei[e];
    int pos = bases[rep * N_NODES + r] + bsums[r >> 8] + (int)rank16[e];
    uint_t p = ((uint_t)f2bf(attr[e]) << 16) | (uint_t)ei[N_EDGES + e];
    packed[pos] = p;
}

// ---------------------------------------------------------------------------
// Owner-computes: out[n] = relu( x[n]@W1 + sum_c T16[c] + (sum attr)*v3 )
// 16 lanes/node, ushort8 (16 B) per lane per neighbor row; MLP-4 gathers.
// ---------------------------------------------------------------------------
__global__ void aggregate_kernel(const int* __restrict__ off,
                                 const int* __restrict__ bsums,
                                 const uint_t* __restrict__ packed,
                                 const ushort_t* __restrict__ T16,
                                 const float* __restrict__ x,
                                 const float* __restrict__ W1,
                                 const float* __restrict__ v3,
                                 float* __restrict__ out) {
    int tid  = blockIdx.x * 256 + threadIdx.x;
    int node = tid >> 4;                 // 16 nodes per block
    int lane = tid & 15;                 // owns cols [8*lane, 8*lane+8)
    int s  = off[node] + bsums[node >> 8];
    int e1 = (node + 1 == N_NODES) ? N_EDGES
                                   : off[node + 1] + bsums[(node + 1) >> 8];
    int deg = e1 - s;

    float acc[8];
#pragma unroll
    for (int i = 0; i < 8; ++i) acc[i] = 0.f;
    float ssum = 0.f;

    for (int base = 0; base < deg; base += 16) {
        int rem = deg - base; if (rem > 16) rem = 16;
        uint_t p = 0;
        if (lane < rem) p = __builtin_nontemporal_load(&packed[s + base + lane]);
        ssum += __uint_as_float(p & 0xFFFF0000u);    // attr (bf16 hi), +0 if idle
        int col = (int)(p & 0xFFFFu);
        int j = 0;
        for (; j + 4 <= rem; j += 4) {
            int c0 = __shfl(col, j + 0, 16);
            int c1 = __shfl(col, j + 1, 16);
            int c2 = __shfl(col, j + 2, 16);
            int c3 = __shfl(col, j + 3, 16);
            short8 t0 = ((const short8*)(T16 + (size_t)c0 * HD))[lane];
            short8 t1 = ((const short8*)(T16 + (size_t)c1 * HD))[lane];
            short8 t2 = ((const short8*)(T16 + (size_t)c2 * HD))[lane];
            short8 t3 = ((const short8*)(T16 + (size_t)c3 * HD))[lane];
#pragma unroll
            for (int i = 0; i < 8; ++i)
                acc[i] += (bf2f((ushort_t)t0[i]) + bf2f((ushort_t)t1[i]))
                        + (bf2f((ushort_t)t2[i]) + bf2f((ushort_t)t3[i]));
        }
        for (; j < rem; ++j) {
            int c = __shfl(col, j, 16);
            short8 tv = ((const short8*)(T16 + (size_t)c * HD))[lane];
#pragma unroll
            for (int i = 0; i < 8; ++i)
                acc[i] += bf2f((ushort_t)tv[i]);
        }
    }
    // reduce ssum across the 16-lane group
    for (int o = 8; o; o >>= 1) ssum += __shfl_xor(ssum, o, 16);

    const float4v* v3p = (const float4v*)v3;
    float4v b0 = v3p[lane * 2], b1 = v3p[lane * 2 + 1];
    acc[0] += ssum * b0[0]; acc[1] += ssum * b0[1];
    acc[2] += ssum * b0[2]; acc[3] += ssum * b0[3];
    acc[4] += ssum * b1[0]; acc[5] += ssum * b1[1];
    acc[6] += ssum * b1[2]; acc[7] += ssum * b1[3];
#pragma unroll
    for (int i = 0; i < IN_DIM; ++i) {
        float xi = x[node * IN_DIM + i];
        const float4v* wp = (const float4v*)(W1 + i * HD);
        float4v w0 = wp[lane * 2], w1 = wp[lane * 2 + 1];
        acc[0] += xi * w0[0]; acc[1] += xi * w0[1];
        acc[2] += xi * w0[2]; acc[3] += xi * w0[3];
        acc[4] += xi * w1[0]; acc[5] += xi * w1[1];
        acc[6] += xi * w1[2]; acc[7] += xi * w1[3];
    }
    float4v o0, o1;
    o0[0] = fmaxf(acc[0], 0.f); o0[1] = fmaxf(acc[1], 0.f);
    o0[2] = fmaxf(acc[2], 0.f); o0[3] = fmaxf(acc[3], 0.f);
    o1[0] = fmaxf(acc[4], 0.f); o1[1] = fmaxf(acc[5], 0.f);
    o1[2] = fmaxf(acc[6], 0.f); o1[3] = fmaxf(acc[7], 0.f);
    float4v* op = (float4v*)(out + (size_t)node * HD);
    __builtin_nontemporal_store(o0, op + lane * 2);
    __builtin_nontemporal_store(o1, op + lane * 2 + 1);
}

extern "C" void kernel_launch(void* const* d_in, const int* in_sizes, int n_in,
                              void* d_out, int out_size, void* d_ws, size_t ws_size,
                              hipStream_t stream) {
    const float* x    = (const float*)d_in[0];   // [N,8]
    const int*   ei   = (const int*)  d_in[1];   // [2,E]
    const float* attr = (const float*)d_in[2];   // [E,1]
    const float* emb  = (const float*)d_in[3];   // [N,128]
    const float* W1   = (const float*)d_in[4];   // [8,128]
    const float* W2   = (const float*)d_in[5];   // [128,128]
    const float* W3   = (const float*)d_in[6];   // [128,128]
    const float* W4   = (const float*)d_in[7];   // [1,128]
    float* out = (float*)d_out;                  // [N,128]

    // workspace layout (~24.2 MB)
    char* w = (char*)d_ws;
    uint_t*   packed = (uint_t*)w;                                   // 3.2 MB
    ushort_t* T16    = (ushort_t*)(w + (size_t)N_EDGES * 4);         // 12.8 MB
    int*      off    = (int*)((char*)T16 + (size_t)N_NODES * HD * 2);// N+4
    int*      bases  = off + N_NODES + 4;        // NREP * N_NODES   // 3.2 MB
    int*      cnt    = bases + NREP * N_NODES;   // NREP * N_NODES   // 3.2 MB
    int*      bsums  = cnt + NREP * N_NODES;     // 256
    float*    v3     = (float*)(bsums + 256);    // 128
    ushort_t* rank16 = (ushort_t*)(v3 + HD);     // 1.6 MB

    phase1_kernel<<<GRID_P1, 256, 0, stream>>>(
        emb, W2, T16, ei, cnt, rank16, W4, W3, v3, bsums);
    scan1_kernel <<<N_SCAN_BLOCKS, 256, 0, stream>>>(cnt, off, bases, bsums);
    fill_kernel  <<<N_HIST_BLOCKS, 256, 0, stream>>>(ei, attr, rank16, bases, bsums, packed);
    aggregate_kernel<<<(N_NODES * 16) / 256, 256, 0, stream>>>(
        off, bsums, packed, T16, x, W1, v3, out);
}